// Round 3
// baseline (354.429 us; speedup 1.0000x reference)
//
#include <hip/hip_runtime.h>
#include <hip/hip_bf16.h>

#define B_  16
#define C_  256
#define H_  48
#define W_  64
#define ND  21           // displacements per axis
#define HW  (H_ * W_)
#define CHW (C_ * H_ * W_)

typedef __attribute__((ext_vector_type(8))) short bf16x8;
typedef __attribute__((ext_vector_type(4))) float f32x4;

__device__ __forceinline__ unsigned int bf16rtne(float f) {
  unsigned int u = __builtin_bit_cast(unsigned int, f);
  return (u + 0x7fffu + ((u >> 16) & 1u)) >> 16;
}

// ---------------------------------------------------------------------------
// Kernel 1: fp32 NCHW -> bf16 NHWC. grid = 2*B*H = 1536 blocks, 256 thr.
// Block (tensor, b, y): reads 64KB (256c x 64x fp32) with 4x256B segments
// per wave-instr, transposes via a 33KB LDS tile [c][x] (stride 66 ushorts:
// odd word stride -> ~2-way on writes; phase-2 gathers use a (g+cq)&7 group
// rotation making the 64-lane u16 read pattern cover all 32 banks), then
// stores bf16 [x][c] rows with 16B fully-coalesced writes.
// ---------------------------------------------------------------------------
__global__ __launch_bounds__(256) void transpose_cvt(
    const float* __restrict__ in1, const float* __restrict__ in2,
    unsigned short* __restrict__ o1, unsigned short* __restrict__ o2) {
  __shared__ unsigned short T[256 * 66];   // [c][x], stride 66 (33 words, odd)

  int blk = blockIdx.x;
  const float* in = in1;
  unsigned short* op = o1;
  if (blk >= B_ * H_) { blk -= B_ * H_; in = in2; op = o2; }
  int y = blk % H_;
  int b = blk / H_;
  int t = threadIdx.x;

  // ---- phase 1: global fp32 -> bf16 -> LDS[c][x] ----
  int u  = t & 15;          // x-quad: x = 4u..4u+3
  int cb = t >> 4;          // c base 0..15, c = cb + 16r
  const float* src = in + (long)b * CHW + y * W_ + u * 4;
#pragma unroll
  for (int r = 0; r < 16; r++) {
    int c = cb + 16 * r;
    float4 v = *(const float4*)(src + (long)c * HW);
    unsigned int p0 = bf16rtne(v.x) | (bf16rtne(v.y) << 16);
    unsigned int p1 = bf16rtne(v.z) | (bf16rtne(v.w) << 16);
    unsigned int* Tw = (unsigned int*)(T + c * 66 + u * 4);  // 4B aligned
    Tw[0] = p0;
    Tw[1] = p1;
  }
  __syncthreads();

  // ---- phase 2: LDS column gather -> coalesced 16B global stores ----
  int x  = t >> 2;          // pixel 0..63
  int cq = t & 3;           // c-chunk: c in [64cq, 64cq+64)
  unsigned short* orow = op + (((long)(b * H_ + y) * W_ + x) * C_);
#pragma unroll
  for (int g = 0; g < 8; g++) {
    int gg = (g + cq) & 7;              // bank-spread rotation
    int c0 = cq * 64 + gg * 8;
    unsigned int w[4];
#pragma unroll
    for (int k2 = 0; k2 < 4; k2++) {
      unsigned int lo = T[(c0 + 2 * k2) * 66 + x];
      unsigned int hi = T[(c0 + 2 * k2 + 1) * 66 + x];
      w[k2] = lo | (hi << 16);
    }
    *(uint4*)(orow + c0) = *(uint4*)w;  // byte off = x*512 + cq*128 + gg*16
  }
}

// ---------------------------------------------------------------------------
// Kernel 2: correlation, NO LDS / NO barriers. grid = B*H = 768, 256 thr.
// Wave w: m-half h = w&1 (x in [32h,32h+32)), dyi parity p = w>>1.
// A-fragments (2 m-tiles x 8 k-granules) live in registers for all 21 dyi.
// Per dyi: 32 B-fragment global loads (L1/L2-served; 16 rows x 64B segments
// per instr) + 64 MFMA 16x16x32 (verified layouts), band-extract epilogue.
// ---------------------------------------------------------------------------
__global__ __launch_bounds__(256, 2) void corr_kernel(
    const unsigned short* __restrict__ At, const unsigned short* __restrict__ Bt,
    float* __restrict__ out) {
  int blk  = blockIdx.x;
  int y    = blk % H_;
  int b    = blk / H_;
  int t    = threadIdx.x;
  int lane = t & 63;
  int wave = t >> 6;
  int l15  = lane & 15;
  int quad = lane >> 4;
  int h    = wave & 1;    // m-half
  int par  = wave >> 1;   // dyi parity

  const unsigned short* Ab = At + (long)(b * H_ + y) * W_ * C_;

  // A fragments in registers: A[m][k], m = 32h + mt*16 + l15, k = (ks*4+quad)*8+j
  bf16x8 afrag[2][8];
#pragma unroll
  for (int mt = 0; mt < 2; mt++)
#pragma unroll
    for (int ks = 0; ks < 8; ks++)
      afrag[mt][ks] = *(const bf16x8*)(Ab + (h * 32 + mt * 16 + l15) * C_ +
                                       (ks * 4 + quad) * 8);

  for (int dyi = par; dyi < ND; dyi += 2) {
    int y2 = y + 2 * dyi - 20;
    long outBase = ((long)(b * (ND * ND) + dyi * ND) * H_ + y) * W_;

    if (y2 < 0 || y2 >= H_) {
      // whole dy-slab zero; this wave fills its x-half for all 21 dxi
      for (int i = lane; i < ND * 32; i += 64) {
        int dxi = i >> 5, x = 32 * h + (i & 31);
        out[outBase + (long)dxi * HW + x] = 0.0f;
      }
      continue;
    }

    const unsigned short* Bb = Bt + (long)(b * H_ + y2) * W_ * C_;
    f32x4 acc[2][4];
#pragma unroll
    for (int mt = 0; mt < 2; mt++)
#pragma unroll
      for (int nt = 0; nt < 4; nt++) acc[mt][nt] = (f32x4){0.f, 0.f, 0.f, 0.f};

#pragma unroll
    for (int ks = 0; ks < 8; ks++) {
      bf16x8 bf[4];
#pragma unroll
      for (int nt = 0; nt < 4; nt++)
        bf[nt] = *(const bf16x8*)(Bb + (nt * 16 + l15) * C_ + (ks * 4 + quad) * 8);
#pragma unroll
      for (int nt = 0; nt < 4; nt++)
#pragma unroll
        for (int mt = 0; mt < 2; mt++)
          acc[mt][nt] = __builtin_amdgcn_mfma_f32_16x16x32_bf16(
              afrag[mt][ks], bf[nt], acc[mt][nt], 0, 0, 0);
    }

    // epilogue: C/D layout col=lane&15 (=xp within nt), row=quad*4+r (=x within mt)
#pragma unroll
    for (int mt = 0; mt < 2; mt++) {
      int xb = 32 * h + mt * 16 + quad * 4;
#pragma unroll
      for (int nt = 0; nt < 4; nt++) {
        int xp = nt * 16 + l15;
#pragma unroll
        for (int r = 0; r < 4; r++) {
          int x = xb + r;
          int dx = xp - x;
          if (dx >= -20 && dx <= 20 && ((dx & 1) == 0)) {
            int dxi = (dx + 20) >> 1;
            out[outBase + (long)dxi * HW + x] = acc[mt][nt][r] * (1.0f / 256.0f);
          }
        }
      }
    }

    // edge zeros (x+dx out of [0,W)): left edges live in h=0, right in h=1
    if (h == 0) {
#pragma unroll
      for (int dxi = 0; dxi < 10; dxi++) {
        int cnt = 20 - 2 * dxi;                    // -dx
        if (lane < cnt) out[outBase + (long)dxi * HW + lane] = 0.0f;
      }
    } else {
#pragma unroll
      for (int dxi = 11; dxi < ND; dxi++) {
        int dx = 2 * dxi - 20;
        if (lane < dx) out[outBase + (long)dxi * HW + (W_ - dx) + lane] = 0.0f;
      }
    }
  }
}

// ---------------------------------------------------------------------------
extern "C" void kernel_launch(void* const* d_in, const int* in_sizes, int n_in,
                              void* d_out, int out_size, void* d_ws, size_t ws_size,
                              hipStream_t stream) {
  (void)in_sizes; (void)n_in; (void)out_size; (void)ws_size;
  const float* in1 = (const float*)d_in[0];
  const float* in2 = (const float*)d_in[1];
  float* out = (float*)d_out;

  unsigned short* o1 = (unsigned short*)d_ws;                    // bf16 [B,H,W,C]
  unsigned short* o2 = o1 + (size_t)B_ * H_ * W_ * C_;           // bf16 [B,H,W,C]

  transpose_cvt<<<2 * B_ * H_, 256, 0, stream>>>(in1, in2, o1, o2);
  corr_kernel<<<B_ * H_, 256, 0, stream>>>(o1, o2, out);
}